// Round 13
// baseline (156.269 us; speedup 1.0000x reference)
//
#include <hip/hip_runtime.h>

#define S_LEN 4096
#define NHEAD 16
#define DHEAD 64
#define HID 1024

typedef float f32x4 __attribute__((ext_vector_type(4)));
typedef float f32x16 __attribute__((ext_vector_type(16)));
typedef unsigned short u16x8 __attribute__((ext_vector_type(8)));
typedef __bf16 bf16x8 __attribute__((ext_vector_type(8)));

__device__ __forceinline__ unsigned short f2bf(float f) {
  union { float f; unsigned u; } x; x.f = f;
  return (unsigned short)((x.u + 0x7FFFu + ((x.u >> 16) & 1u)) >> 16);
}
__device__ __forceinline__ float bf2f(unsigned short u) {
  union { unsigned u; float f; } x; x.u = ((unsigned)u) << 16;
  return x.f;
}
__device__ __forceinline__ f32x4 mfma16(u16x8 a, u16x8 b, f32x4 c) {
  return __builtin_amdgcn_mfma_f32_16x16x32_bf16(
      __builtin_bit_cast(bf16x8, a), __builtin_bit_cast(bf16x8, b), c, 0, 0, 0);
}
__device__ __forceinline__ f32x16 mfma32(u16x8 a, u16x8 b, f32x16 c) {
  return __builtin_amdgcn_mfma_f32_32x32x16_bf16(
      __builtin_bit_cast(bf16x8, a), __builtin_bit_cast(bf16x8, b), c, 0, 0, 0);
}
__device__ __forceinline__ void gload16(const void* g, void* l) {
  __builtin_amdgcn_global_load_lds(
      (const __attribute__((address_space(1))) void*)g,
      (__attribute__((address_space(3))) void*)l, 16, 0, 0);
}
// swap: a' = [a.lanes0-31 | b.lanes0-31], b' = [a.lanes32-63 | b.lanes32-63]
__device__ __forceinline__ void permswap(unsigned& a, unsigned& b) {
#if __has_builtin(__builtin_amdgcn_permlane32_swap)
  typedef unsigned u32x2 __attribute__((ext_vector_type(2)));
  u32x2 r = __builtin_amdgcn_permlane32_swap(a, b, false, false);
  a = r[0]; b = r[1];
#else
  asm volatile("v_permlane32_swap_b32 %0, %1" : "+v"(a), "+v"(b));
#endif
}
__device__ __forceinline__ unsigned cvtpk(float lo, float hi) {
  unsigned r;
  asm("v_cvt_pk_bf16_f32 %0, %1, %2" : "=v"(r) : "v"(lo), "v"(hi));
  return r;
}
// raw hardware 2^x (single trans op; library exp2f is a multi-op sequence)
__device__ __forceinline__ float fexp2(float x) {
  float r;
  asm("v_exp_f32 %0, %1" : "=v"(r) : "v"(x));
  return r;
}

// ---------- fused fp32 -> bf16 convert for all three tensors ----------
__global__ void k_cvt_all(const float4* __restrict__ x, const float4* __restrict__ wq,
                          const float4* __restrict__ wo, ushort4* __restrict__ xb,
                          ushort4* __restrict__ wqb, ushort4* __restrict__ wob) {
  int i = blockIdx.x * blockDim.x + threadIdx.x;  // 0..2097151
  const float4* src; ushort4* dst; int off;
  if (i < 1048576)      { src = x;  dst = xb;  off = i; }
  else if (i < 1835008) { src = wq; dst = wqb; off = i - 1048576; }
  else                  { src = wo; dst = wob; off = i - 1835008; }
  float4 v = src[off];
  ushort4 o;
  o.x = f2bf(v.x); o.y = f2bf(v.y); o.z = f2bf(v.z); o.w = f2bf(v.w);
  dst[off] = o;
}

// ---------- rope + split: Q row-major [H][S][64]; K fragment-major
// Kf[h][t32][c:4][hf:2][kv:32][e:8] = K[h][t32*32+kv][c*16+hf*8+e], pre-scaled 0.125*log2e
__global__ void k_rope_split(const unsigned short* __restrict__ qkv,
                             unsigned short* __restrict__ Q,
                             unsigned short* __restrict__ Kf) {
  int s = blockIdx.x;
  int t = threadIdx.x;  // 512 threads
  int h = t >> 5, i = t & 31;
  // inv_freq = 10000^(-i/32) = 2^(-i * log2(10000)/32)
  float inv = fexp2(-(float)i * 0.4152410118609203f);
  float ang = (float)s * inv;
  float sn, cs;
  __sincosf(ang, &sn, &cs);
  const unsigned short* row = qkv + (size_t)s * 3072;
  float q1 = bf2f(row[h * 64 + i]);
  float q2 = bf2f(row[h * 64 + i + 32]);
  float k1 = bf2f(row[1024 + h * 64 + i]);
  float k2 = bf2f(row[1024 + h * 64 + i + 32]);
  const float ksc = 0.125f * 1.44269504f;
  size_t qo = ((size_t)h * S_LEN + s) * 64 + i;
  Q[qo]      = f2bf(q1 * cs - q2 * sn);
  Q[qo + 32] = f2bf(q2 * cs + q1 * sn);
  // K at d=i and d=i+32 (c differs by 2)
  int t32 = s >> 5, kv = s & 31;
  size_t ko = ((((size_t)h * 128 + t32) * 4 + (i >> 4)) * 2 + ((i >> 3) & 1)) * 256 + kv * 8 + (i & 7);
  Kf[ko]        = f2bf((k1 * cs - k2 * sn) * ksc);
  Kf[ko + 1024] = f2bf((k2 * cs + k1 * sn) * ksc);
}

// ---------- V to fragment-major: Vf[h][t32][kc:2][hfv:2][d:64][e:8] = V[t32*32+kc*16+hfv*8+e][h*64+d]
__global__ void k_vt(const unsigned short* __restrict__ qkv,
                     unsigned short* __restrict__ Vf) {
  __shared__ unsigned short tile[64][65];
  int st = blockIdx.x, h = blockIdx.y;
  int t = threadIdx.x;  // 256
  int r = t >> 2, c0 = (t & 3) * 16;
  const unsigned short* src = qkv + (size_t)(st * 64 + r) * 3072 + 2048 + h * 64 + c0;
  u16x8 a = *(const u16x8*)src;
  u16x8 b = *(const u16x8*)(src + 8);
#pragma unroll
  for (int j = 0; j < 8; ++j) { tile[r][c0 + j] = a[j]; tile[r][c0 + 8 + j] = b[j]; }
  __syncthreads();
#pragma unroll
  for (int pass = 0; pass < 2; ++pass) {
    int task = t + pass * 256;        // task = o*64 + d
    int o = task >> 6, d = task & 63; // o = s'>>3 within the 64-row tile
    int t32 = st * 2 + (o >> 2), kc = (o >> 1) & 1, hfv = o & 1;
    u16x8 v;
#pragma unroll
    for (int e = 0; e < 8; ++e) v[e] = tile[o * 8 + e][d];
    *(u16x8*)(Vf + (((((size_t)h * 128 + t32) * 2 + kc) * 2 + hfv) * 64 + d) * 8) = v;
  }
}

// ---------- GEMM: C[M][N] = A[M][K] * B[N][K]^T ----------
// BK=32: LDS 32 KB -> 5 blocks/CU (all 768 QKV blocks co-resident; TLP hides the
// barrier drain) and 64 B LDS rows -> 2-way bank aliasing only (free), vs the
// 16-way conflict of 128 B rows.
__device__ __forceinline__ void stc(float* p, float v) { *p = v; }
__device__ __forceinline__ void stc(unsigned short* p, float v) { *p = f2bf(v); }

template <typename OutT>
__global__ __launch_bounds__(256, 5) void gemm_bt(
    const unsigned short* __restrict__ A, const unsigned short* __restrict__ B,
    OutT* __restrict__ C, int M, int N, int K) {
  __shared__ __attribute__((aligned(16))) unsigned short As[2][128][32];
  __shared__ __attribute__((aligned(16))) unsigned short Bs[2][128][32];
  const int tid = threadIdx.x;
  const int w = tid >> 6, lane = tid & 63;
  const int bm = blockIdx.y * 128, bn = blockIdx.x * 128;
  const int wr = w >> 1, wc = w & 1;
  const int l16 = lane >> 2;           // 16 rows per gload16 call
  const int c4 = (lane & 3) * 8;       // 4 slots of 8 elems
  f32x4 acc[4][4] = {};

  auto stage = [&](int buf, int k0) {
#pragma unroll
    for (int c = 0; c < 2; ++c) {
      int row = w * 32 + c * 16;
      gload16(A + (size_t)(bm + row + l16) * K + k0 + c4, &As[buf][row][0]);
      gload16(B + (size_t)(bn + row + l16) * K + k0 + c4, &Bs[buf][row][0]);
    }
  };

  const int nk = K >> 5;
  stage(0, 0);
  int cur = 0;
  for (int kt = 0; kt < nk; ++kt) {
    __syncthreads();
    if (kt + 1 < nk) stage(cur ^ 1, (kt + 1) << 5);
    u16x8 af[4], bfr[4];
#pragma unroll
    for (int m = 0; m < 4; ++m)
      af[m] = *(const u16x8*)&As[cur][wr * 64 + m * 16 + (lane & 15)][(lane >> 4) * 8];
#pragma unroll
    for (int n = 0; n < 4; ++n)
      bfr[n] = *(const u16x8*)&Bs[cur][wc * 64 + n * 16 + (lane & 15)][(lane >> 4) * 8];
#pragma unroll
    for (int m = 0; m < 4; ++m)
#pragma unroll
      for (int n = 0; n < 4; ++n)
        acc[m][n] = mfma16(af[m], bfr[n], acc[m][n]);
    cur ^= 1;
  }
#pragma unroll
  for (int m = 0; m < 4; ++m) {
    int row = bm + wr * 64 + m * 16 + (lane >> 4) * 4;
#pragma unroll
    for (int n = 0; n < 4; ++n) {
      int col = bn + wc * 64 + n * 16 + (lane & 15);
#pragma unroll
      for (int j = 0; j < 4; ++j) stc(&C[(size_t)(row + j) * N + col], acc[m][n][j]);
    }
  }
}

// ---------- process kv-steps [t0, t1) of a causal q-tile (nst = full step count) ----------
__device__ __forceinline__ void attn_range(
    const unsigned short* __restrict__ kfb, const unsigned short* __restrict__ vfb,
    const u16x8* qf, f32x16& accA, f32x16& accB, float& l_own,
    int t0, int t1, int nst, int qg, int hf, int kOffBase, int vOffBase) {
  u16x8 ka[4], kb_[4], kc2[4], va[4], vb_[4], vc2[4];
#define LOADK(dst, t)                                                         \
  {                                                                           \
    const unsigned short* p_ = kfb + (size_t)(t) * 2048 + kOffBase;           \
    dst[0] = *(const u16x8*)(p_);                                             \
    dst[1] = *(const u16x8*)(p_ + 512);                                       \
    dst[2] = *(const u16x8*)(p_ + 1024);                                      \
    dst[3] = *(const u16x8*)(p_ + 1536);                                      \
  }
#define LOADV(dst, t)                                                         \
  {                                                                           \
    const unsigned short* p_ = vfb + (size_t)(t) * 2048 + vOffBase;           \
    dst[0] = *(const u16x8*)(p_);                                             \
    dst[1] = *(const u16x8*)(p_ + 256);                                       \
    dst[2] = *(const u16x8*)(p_ + 1024);                                      \
    dst[3] = *(const u16x8*)(p_ + 1280);                                      \
  }
#define STEP(t, kc_, vc_, kn_, vn_)                                           \
  {                                                                           \
    const int tn = ((t) + 2 < t1) ? (t) + 2 : t1 - 1;                         \
    LOADK(kn_, tn);                                                           \
    LOADV(vn_, tn);                                                           \
    f32x16 sc = {};                                                           \
    __builtin_amdgcn_s_setprio(1);                                            \
    _Pragma("unroll") for (int c = 0; c < 4; ++c) sc = mfma32(kc_[c], qf[c], sc); \
    __builtin_amdgcn_s_setprio(0);                                            \
    if ((t) == nst - 1) {  /* diagonal tile: mask kv > q */                   \
      _Pragma("unroll") for (int r = 0; r < 16; ++r) {                        \
        int kvl = (t) * 32 + (r & 3) + 8 * (r >> 2) + 4 * hf;                 \
        if (kvl > qg) sc[r] = -1e30f;                                         \
      }                                                                       \
    }                                                                         \
    float p[16];                                                              \
    _Pragma("unroll") for (int r = 0; r < 16; ++r) p[r] = fexp2(sc[r]);       \
    l_own += (((p[0] + p[1]) + (p[2] + p[3])) + ((p[4] + p[5]) + (p[6] + p[7]))) + \
             (((p[8] + p[9]) + (p[10] + p[11])) + ((p[12] + p[13]) + (p[14] + p[15]))); \
    unsigned dw[8];                                                           \
    _Pragma("unroll") for (int k = 0; k < 8; ++k) dw[k] = cvtpk(p[2 * k], p[2 * k + 1]); \
    __builtin_amdgcn_s_setprio(1);                                            \
    _Pragma("unroll") for (int kc = 0; kc < 2; ++kc) {                        \
      unsigned x0 = dw[4 * kc + 0], x1 = dw[4 * kc + 1];                      \
      unsigned y0 = dw[4 * kc + 2], y1 = dw[4 * kc + 3];                      \
      permswap(x0, y0);                                                       \
      permswap(x1, y1);                                                       \
      union { u16x8 v; unsigned u[4]; } pf;                                   \
      pf.u[0] = x0; pf.u[1] = x1; pf.u[2] = y0; pf.u[3] = y1;                 \
      accA = mfma32(vc_[kc * 2 + 0], pf.v, accA);                             \
      accB = mfma32(vc_[kc * 2 + 1], pf.v, accB);                             \
    }                                                                         \
    __builtin_amdgcn_s_setprio(0);                                            \
  }

  LOADK(ka, t0);
  LOADV(va, t0);
  {
    const int t1c = (t0 + 1 < t1) ? t0 + 1 : t1 - 1;
    LOADK(kb_, t1c);
    LOADV(vb_, t1c);
  }
  int t = t0;
  while (true) {
    STEP(t, ka, va, kc2, vc2);
    if (++t >= t1) break;
    STEP(t, kb_, vb_, ka, va);
    if (++t >= t1) break;
    STEP(t, kc2, vc2, kb_, vb_);
    if (++t >= t1) break;
  }
#undef STEP
#undef LOADK
#undef LOADV
}

// ---------- normalize + transpose (via private LDS) + coalesced O store ----------
__device__ __forceinline__ void attn_epilogue(
    const f32x16& accA, const f32x16& accB, float l_own, char* eb,
    unsigned short* __restrict__ O, int h, int qb, int wr, int q31, int hf) {
  float l_run;
  {
    unsigned a = __float_as_uint(l_own), b = a;
    permswap(a, b);
    l_run = __uint_as_float(a) + __uint_as_float(b);
  }
  const float inv = 1.0f / l_run;
#pragma unroll
  for (int dblk = 0; dblk < 2; ++dblk) {
#pragma unroll
    for (int tt = 0; tt < 4; ++tt) {
      float a0, a1, a2, a3;
      if (dblk == 0) { a0 = accA[4 * tt]; a1 = accA[4 * tt + 1]; a2 = accA[4 * tt + 2]; a3 = accA[4 * tt + 3]; }
      else           { a0 = accB[4 * tt]; a1 = accB[4 * tt + 1]; a2 = accB[4 * tt + 2]; a3 = accB[4 * tt + 3]; }
      unsigned d0 = cvtpk(a0 * inv, a1 * inv);
      unsigned d1 = cvtpk(a2 * inv, a3 * inv);
      int dbase = dblk * 32 + 8 * tt + 4 * hf;
      int off = (q31 * 128 + dbase * 2) ^ ((q31 & 7) << 4);
      *(uint2*)(eb + off) = make_uint2(d0, d1);
    }
  }
  const int lane = hf * 32 + q31;
  // same-wave RAW on LDS: compiler inserts lgkmcnt
#pragma unroll
  for (int pass = 0; pass < 4; ++pass) {
    int q = (lane >> 3) + pass * 8;
    int c8 = lane & 7;
    u16x8 vv = *(const u16x8*)(eb + ((q * 128 + c8 * 16) ^ ((q & 7) << 4)));
    *(u16x8*)(O + (size_t)(qb + wr * 32 + q) * HID + h * 64 + c8 * 8) = vv;
  }
}

// ---------- flash attention (causal): balanced pair + kv-split, 8 waves/block ----------
__global__ __launch_bounds__(512) void flash_attn(
    const unsigned short* __restrict__ Q,
    const unsigned short* __restrict__ Kf,
    const unsigned short* __restrict__ Vf,
    unsigned short* __restrict__ O) {
  __shared__ __attribute__((aligned(16))) unsigned short ebuf[8][2048];  // 32 KB
  __shared__ float part[4][64][33];                                      // 33.8 KB
  const int tid = threadIdx.x;
  const int wv = tid >> 6, lane = tid & 63;
  const int wr = wv & 3, role = wv >> 2;
  const int q31 = lane & 31, hf = lane >> 5;
  const int h = blockIdx.x;          // XCD = h % 8 -> K/V L2-resident (2 heads/XCD)
  const int p = blockIdx.y;
  const int tileB = 31 - p;
  const int nstA = 4 * p + wr + 1;
  const int nstB = 4 * tileB + wr + 1;
  const int cut = 62 - 4 * p;        // head/tail split of tile B (>=2 for p<=15)

  const unsigned short* kfb = Kf + (size_t)h * 128 * 2048;
  const unsigned short* vfb = Vf + (size_t)h * 128 * 2048;
  const int kOffBase = hf * 256 + q31 * 8;
  const int vOffBase = hf * 512 + q31 * 8;
  char* eb = (char*)&ebuf[wv][0];

  const int qgB = tileB * 128 + wr * 32 + q31;
  u16x8 qfB[4];
  {
    const unsigned short* qp = Q + ((size_t)h * S_LEN + qgB) * 64 + hf * 8;
#pragma unroll
    for (int c = 0; c < 4; ++c) qfB[c] = *(const u16x8*)(qp + c * 16);
  }

  if (role == 0) {
    // ---- tile A (= p) full triangle ----
    const int qgA = p * 128 + wr * 32 + q31;
    u16x8 qfA[4];
    {
      const unsigned short* qp = Q + ((size_t)h * S_LEN + qgA) * 64 + hf * 8;
#pragma unroll
      for (int c = 0; c < 4; ++c) qfA[c] = *(const u16x8*)(qp + c * 16);
    }
    f32x16 accA = {}, accB = {};
    float l_own = 0.f;
    attn_range(kfb, vfb, qfA, accA, accB, l_own, 0, nstA, nstA, qgA, hf, kOffBase, vOffBase);
    attn_epilogue(accA, accB, l_own, eb, O, h, p * 128, wr, q31, hf);
    // ---- tile B head [0, cut) ----
    f32x16 bA = {}, bB = {};
    float bl = 0.f;
    attn_range(kfb, vfb, qfB, bA, bB, bl, 0, cut, nstB, qgB, hf, kOffBase, vOffBase);
    float* pp = &part[wr][lane][0];
#pragma unroll
    for (int r = 0; r < 16; ++r) { pp[r] = bA[r]; pp[16 + r] = bB[r]; }
    pp[32] = bl;
    __syncthreads();
  } else {
    // ---- tile B tail [cut, nstB) (includes diagonal) ----
    f32x16 bA = {}, bB = {};
    float bl = 0.f;
    attn_range(kfb, vfb, qfB, bA, bB, bl, cut, nstB, nstB, qgB, hf, kOffBase, vOffBase);
    __syncthreads();
    const float* pp = &part[wr][lane][0];
#pragma unroll
    for (int r = 0; r < 16; ++r) { bA[r] += pp[r]; bB[r] += pp[16 + r]; }
    bl += pp[32];
    attn_epilogue(bA, bB, bl, eb, O, h, tileB * 128, wr, q31, hf);
  }
}

extern "C" void kernel_launch(void* const* d_in, const int* in_sizes, int n_in,
                              void* d_out, int out_size, void* d_ws, size_t ws_size,
                              hipStream_t stream) {
  const float* x = (const float*)d_in[0];       // [4096][1024]
  const float* w_qkv = (const float*)d_in[1];   // [3072][1024]
  const float* w_out = (const float*)d_in[2];   // [1024][1024]
  float* out = (float*)d_out;                   // [4096][1024] f32
  char* ws = (char*)d_ws;

  unsigned short* xb    = (unsigned short*)(ws + 0);          // 8 MB
  unsigned short* wqkvb = (unsigned short*)(ws + 8388608);    // 6 MB
  unsigned short* woutb = (unsigned short*)(ws + 14680064);   // 2 MB
  unsigned short* qkvb  = (unsigned short*)(ws + 16777216);   // 24 MB [S][3072]
  unsigned short* Qb    = (unsigned short*)(ws + 41943040);   // 8 MB [H][S][64]
  unsigned short* Kfb   = (unsigned short*)(ws + 50331648);   // 8 MB fragment-major
  unsigned short* Vfb   = (unsigned short*)(ws + 58720256);   // 8 MB fragment-major
  unsigned short* attnb = (unsigned short*)(ws + 67108864);   // 8 MB [S][1024]

  k_cvt_all<<<dim3(8192), dim3(256), 0, stream>>>(
      (const float4*)x, (const float4*)w_qkv, (const float4*)w_out,
      (ushort4*)xb, (ushort4*)wqkvb, (ushort4*)woutb);

  gemm_bt<unsigned short><<<dim3(24, 32), dim3(256), 0, stream>>>(xb, wqkvb, qkvb, 4096, 3072, 1024);

  k_rope_split<<<dim3(4096), dim3(512), 0, stream>>>(qkvb, Qb, Kfb);
  k_vt<<<dim3(64, 16), dim3(256), 0, stream>>>(qkvb, Vfb);

  // balanced pair + kv-split grid: blockId = h + 16*p -> XCD = h%8
  flash_attn<<<dim3(16, 16), dim3(512), 0, stream>>>(Qb, Kfb, Vfb, attnb);

  gemm_bt<float><<<dim3(8, 32), dim3(256), 0, stream>>>(attnb, woutb, out, 4096, 1024, 1024);
}

// Round 14
// 130.088 us; speedup vs baseline: 1.2013x; 1.2013x over previous
//
#include <hip/hip_runtime.h>

#define S_LEN 4096
#define NHEAD 16
#define DHEAD 64
#define HID 1024

typedef float f32x4 __attribute__((ext_vector_type(4)));
typedef float f32x16 __attribute__((ext_vector_type(16)));
typedef unsigned short u16x8 __attribute__((ext_vector_type(8)));
typedef __bf16 bf16x8 __attribute__((ext_vector_type(8)));

__device__ __forceinline__ unsigned short f2bf(float f) {
  union { float f; unsigned u; } x; x.f = f;
  return (unsigned short)((x.u + 0x7FFFu + ((x.u >> 16) & 1u)) >> 16);
}
__device__ __forceinline__ float bf2f(unsigned short u) {
  union { unsigned u; float f; } x; x.u = ((unsigned)u) << 16;
  return x.f;
}
__device__ __forceinline__ f32x4 mfma16(u16x8 a, u16x8 b, f32x4 c) {
  return __builtin_amdgcn_mfma_f32_16x16x32_bf16(
      __builtin_bit_cast(bf16x8, a), __builtin_bit_cast(bf16x8, b), c, 0, 0, 0);
}
__device__ __forceinline__ f32x16 mfma32(u16x8 a, u16x8 b, f32x16 c) {
  return __builtin_amdgcn_mfma_f32_32x32x16_bf16(
      __builtin_bit_cast(bf16x8, a), __builtin_bit_cast(bf16x8, b), c, 0, 0, 0);
}
__device__ __forceinline__ void gload16(const void* g, void* l) {
  __builtin_amdgcn_global_load_lds(
      (const __attribute__((address_space(1))) void*)g,
      (__attribute__((address_space(3))) void*)l, 16, 0, 0);
}
// swap: a' = [a.lanes0-31 | b.lanes0-31], b' = [a.lanes32-63 | b.lanes32-63]
__device__ __forceinline__ void permswap(unsigned& a, unsigned& b) {
#if __has_builtin(__builtin_amdgcn_permlane32_swap)
  typedef unsigned u32x2 __attribute__((ext_vector_type(2)));
  u32x2 r = __builtin_amdgcn_permlane32_swap(a, b, false, false);
  a = r[0]; b = r[1];
#else
  asm volatile("v_permlane32_swap_b32 %0, %1" : "+v"(a), "+v"(b));
#endif
}
__device__ __forceinline__ unsigned cvtpk(float lo, float hi) {
  unsigned r;
  asm("v_cvt_pk_bf16_f32 %0, %1, %2" : "=v"(r) : "v"(lo), "v"(hi));
  return r;
}
// raw hardware 2^x (single trans op; library exp2f is a multi-op sequence)
__device__ __forceinline__ float fexp2(float x) {
  float r;
  asm("v_exp_f32 %0, %1" : "=v"(r) : "v"(x));
  return r;
}

// ---------- fused fp32 -> bf16 convert for all three tensors ----------
__global__ void k_cvt_all(const float4* __restrict__ x, const float4* __restrict__ wq,
                          const float4* __restrict__ wo, ushort4* __restrict__ xb,
                          ushort4* __restrict__ wqb, ushort4* __restrict__ wob) {
  int i = blockIdx.x * blockDim.x + threadIdx.x;  // 0..2097151
  const float4* src; ushort4* dst; int off;
  if (i < 1048576)      { src = x;  dst = xb;  off = i; }
  else if (i < 1835008) { src = wq; dst = wqb; off = i - 1048576; }
  else                  { src = wo; dst = wob; off = i - 1835008; }
  float4 v = src[off];
  ushort4 o;
  o.x = f2bf(v.x); o.y = f2bf(v.y); o.z = f2bf(v.z); o.w = f2bf(v.w);
  dst[off] = o;
}

// ---------- rope + split: Q row-major [H][S][64]; K fragment-major
// Kf[h][t32][c:4][hf:2][kv:32][e:8] = K[h][t32*32+kv][c*16+hf*8+e], pre-scaled 0.125*log2e
__global__ void k_rope_split(const unsigned short* __restrict__ qkv,
                             unsigned short* __restrict__ Q,
                             unsigned short* __restrict__ Kf) {
  int s = blockIdx.x;
  int t = threadIdx.x;  // 512 threads
  int h = t >> 5, i = t & 31;
  // inv_freq = 10000^(-i/32) = 2^(-i * log2(10000)/32)
  float inv = fexp2(-(float)i * 0.4152410118609203f);
  float ang = (float)s * inv;
  float sn, cs;
  __sincosf(ang, &sn, &cs);
  const unsigned short* row = qkv + (size_t)s * 3072;
  float q1 = bf2f(row[h * 64 + i]);
  float q2 = bf2f(row[h * 64 + i + 32]);
  float k1 = bf2f(row[1024 + h * 64 + i]);
  float k2 = bf2f(row[1024 + h * 64 + i + 32]);
  const float ksc = 0.125f * 1.44269504f;
  size_t qo = ((size_t)h * S_LEN + s) * 64 + i;
  Q[qo]      = f2bf(q1 * cs - q2 * sn);
  Q[qo + 32] = f2bf(q2 * cs + q1 * sn);
  // K at d=i and d=i+32 (c differs by 2)
  int t32 = s >> 5, kv = s & 31;
  size_t ko = ((((size_t)h * 128 + t32) * 4 + (i >> 4)) * 2 + ((i >> 3) & 1)) * 256 + kv * 8 + (i & 7);
  Kf[ko]        = f2bf((k1 * cs - k2 * sn) * ksc);
  Kf[ko + 1024] = f2bf((k2 * cs + k1 * sn) * ksc);
}

// ---------- V to fragment-major: Vf[h][t32][kc:2][hfv:2][d:64][e:8] = V[t32*32+kc*16+hfv*8+e][h*64+d]
__global__ void k_vt(const unsigned short* __restrict__ qkv,
                     unsigned short* __restrict__ Vf) {
  __shared__ unsigned short tile[64][65];
  int st = blockIdx.x, h = blockIdx.y;
  int t = threadIdx.x;  // 256
  int r = t >> 2, c0 = (t & 3) * 16;
  const unsigned short* src = qkv + (size_t)(st * 64 + r) * 3072 + 2048 + h * 64 + c0;
  u16x8 a = *(const u16x8*)src;
  u16x8 b = *(const u16x8*)(src + 8);
#pragma unroll
  for (int j = 0; j < 8; ++j) { tile[r][c0 + j] = a[j]; tile[r][c0 + 8 + j] = b[j]; }
  __syncthreads();
#pragma unroll
  for (int pass = 0; pass < 2; ++pass) {
    int task = t + pass * 256;        // task = o*64 + d
    int o = task >> 6, d = task & 63; // o = s'>>3 within the 64-row tile
    int t32 = st * 2 + (o >> 2), kc = (o >> 1) & 1, hfv = o & 1;
    u16x8 v;
#pragma unroll
    for (int e = 0; e < 8; ++e) v[e] = tile[o * 8 + e][d];
    *(u16x8*)(Vf + (((((size_t)h * 128 + t32) * 2 + kc) * 2 + hfv) * 64 + d) * 8) = v;
  }
}

// ---------- GEMM: C[M][N] = A[M][K] * B[N][K]^T ----------
// BK=32, TRIPLE-buffered LDS (48 KB -> 3 blocks/CU; QKV grid 768 = fully
// co-resident), counted s_waitcnt vmcnt(4) + raw s_barrier: prefetched tiles
// stay in flight across barriers (no vmcnt(0) drain). LDS slot swizzle
// s_phys = (k_slot ^ (row>>1)) & 3 (pre-swizzled global src, XOR'd reads):
// 2-way bank aliasing only (free).
__device__ __forceinline__ void stc(float* p, float v) { *p = v; }
__device__ __forceinline__ void stc(unsigned short* p, float v) { *p = f2bf(v); }

template <typename OutT>
__global__ __launch_bounds__(256, 3) void gemm_bt(
    const unsigned short* __restrict__ A, const unsigned short* __restrict__ B,
    OutT* __restrict__ C, int M, int N, int K) {
  __shared__ __attribute__((aligned(16))) unsigned short As[3][128][32];
  __shared__ __attribute__((aligned(16))) unsigned short Bs[3][128][32];
  const int tid = threadIdx.x;
  const int w = tid >> 6, lane = tid & 63;
  const int bm = blockIdx.y * 128, bn = blockIdx.x * 128;
  const int wr = w >> 1, wc = w & 1;
  const int l16 = lane >> 2;                              // row within 16-row chunk
  const int c4s = ((lane & 3) ^ ((lane >> 3) & 3)) * 8;   // pre-swizzled source slot (elems)
  f32x4 acc[4][4] = {};

  auto stage = [&](int buf, int kt) {
    const int k0 = kt << 5;
#pragma unroll
    for (int c = 0; c < 2; ++c) {
      int row = w * 32 + c * 16;
      gload16(A + (size_t)(bm + row + l16) * K + k0 + c4s, &As[buf][row][0]);
      gload16(B + (size_t)(bn + row + l16) * K + k0 + c4s, &Bs[buf][row][0]);
    }
  };

  const int nk = K >> 5;
  stage(0, 0);
  stage(1, 1);
  int cur = 0;
  for (int kt = 0; kt < nk; ++kt) {
    // wait only tile kt's 4 loads; tile kt+1's stay in flight across the barrier
    asm volatile("s_waitcnt vmcnt(4)" ::: "memory");
    __builtin_amdgcn_sched_barrier(0);
    __builtin_amdgcn_s_barrier();
    __builtin_amdgcn_sched_barrier(0);
    {
      const int sbuf = (cur + 2 >= 3) ? cur - 1 : cur + 2;
      const int stile = (kt + 2 < nk) ? kt + 2 : nk - 1;  // clamp: keeps vmcnt constant
      stage(sbuf, stile);
    }
    // fragment reads: physical slot = (k_slot ^ (row>>1)) & 3; row&15 == lane&15
    const int sph = (((lane >> 4) ^ (lane >> 1)) & 3) * 16;  // byte offset within row
    u16x8 af[4], bfr[4];
#pragma unroll
    for (int m = 0; m < 4; ++m) {
      int row = wr * 64 + m * 16 + (lane & 15);
      af[m] = *(const u16x8*)((const char*)&As[cur][0][0] + row * 64 + sph);
    }
#pragma unroll
    for (int n = 0; n < 4; ++n) {
      int row = wc * 64 + n * 16 + (lane & 15);
      bfr[n] = *(const u16x8*)((const char*)&Bs[cur][0][0] + row * 64 + sph);
    }
#pragma unroll
    for (int m = 0; m < 4; ++m)
#pragma unroll
      for (int n = 0; n < 4; ++n)
        acc[m][n] = mfma16(af[m], bfr[n], acc[m][n]);
    cur = (cur + 1 == 3) ? 0 : cur + 1;
  }
#pragma unroll
  for (int m = 0; m < 4; ++m) {
    int row = bm + wr * 64 + m * 16 + (lane >> 4) * 4;
#pragma unroll
    for (int n = 0; n < 4; ++n) {
      int col = bn + wc * 64 + n * 16 + (lane & 15);
#pragma unroll
      for (int j = 0; j < 4; ++j) stc(&C[(size_t)(row + j) * N + col], acc[m][n][j]);
    }
  }
}

// ---------- process kv-steps [t0, t1) of a causal q-tile (nst = full step count) ----------
__device__ __forceinline__ void attn_range(
    const unsigned short* __restrict__ kfb, const unsigned short* __restrict__ vfb,
    const u16x8* qf, f32x16& accA, f32x16& accB, float& l_own,
    int t0, int t1, int nst, int qg, int hf, int kOffBase, int vOffBase) {
  u16x8 ka[4], kb_[4], kc2[4], va[4], vb_[4], vc2[4];
#define LOADK(dst, t)                                                         \
  {                                                                           \
    const unsigned short* p_ = kfb + (size_t)(t) * 2048 + kOffBase;           \
    dst[0] = *(const u16x8*)(p_);                                             \
    dst[1] = *(const u16x8*)(p_ + 512);                                       \
    dst[2] = *(const u16x8*)(p_ + 1024);                                      \
    dst[3] = *(const u16x8*)(p_ + 1536);                                      \
  }
#define LOADV(dst, t)                                                         \
  {                                                                           \
    const unsigned short* p_ = vfb + (size_t)(t) * 2048 + vOffBase;           \
    dst[0] = *(const u16x8*)(p_);                                             \
    dst[1] = *(const u16x8*)(p_ + 256);                                       \
    dst[2] = *(const u16x8*)(p_ + 1024);                                      \
    dst[3] = *(const u16x8*)(p_ + 1280);                                      \
  }
#define STEP(t, kc_, vc_, kn_, vn_)                                           \
  {                                                                           \
    const int tn = ((t) + 2 < t1) ? (t) + 2 : t1 - 1;                         \
    LOADK(kn_, tn);                                                           \
    LOADV(vn_, tn);                                                           \
    f32x16 sc = {};                                                           \
    __builtin_amdgcn_s_setprio(1);                                            \
    _Pragma("unroll") for (int c = 0; c < 4; ++c) sc = mfma32(kc_[c], qf[c], sc); \
    __builtin_amdgcn_s_setprio(0);                                            \
    if ((t) == nst - 1) {  /* diagonal tile: mask kv > q */                   \
      _Pragma("unroll") for (int r = 0; r < 16; ++r) {                        \
        int kvl = (t) * 32 + (r & 3) + 8 * (r >> 2) + 4 * hf;                 \
        if (kvl > qg) sc[r] = -1e30f;                                         \
      }                                                                       \
    }                                                                         \
    float p[16];                                                              \
    _Pragma("unroll") for (int r = 0; r < 16; ++r) p[r] = fexp2(sc[r]);       \
    l_own += (((p[0] + p[1]) + (p[2] + p[3])) + ((p[4] + p[5]) + (p[6] + p[7]))) + \
             (((p[8] + p[9]) + (p[10] + p[11])) + ((p[12] + p[13]) + (p[14] + p[15]))); \
    unsigned dw[8];                                                           \
    _Pragma("unroll") for (int k = 0; k < 8; ++k) dw[k] = cvtpk(p[2 * k], p[2 * k + 1]); \
    __builtin_amdgcn_s_setprio(1);                                            \
    _Pragma("unroll") for (int kc = 0; kc < 2; ++kc) {                        \
      unsigned x0 = dw[4 * kc + 0], x1 = dw[4 * kc + 1];                      \
      unsigned y0 = dw[4 * kc + 2], y1 = dw[4 * kc + 3];                      \
      permswap(x0, y0);                                                       \
      permswap(x1, y1);                                                       \
      union { u16x8 v; unsigned u[4]; } pf;                                   \
      pf.u[0] = x0; pf.u[1] = x1; pf.u[2] = y0; pf.u[3] = y1;                 \
      accA = mfma32(vc_[kc * 2 + 0], pf.v, accA);                             \
      accB = mfma32(vc_[kc * 2 + 1], pf.v, accB);                             \
    }                                                                         \
    __builtin_amdgcn_s_setprio(0);                                            \
  }

  LOADK(ka, t0);
  LOADV(va, t0);
  {
    const int t1c = (t0 + 1 < t1) ? t0 + 1 : t1 - 1;
    LOADK(kb_, t1c);
    LOADV(vb_, t1c);
  }
  int t = t0;
  while (true) {
    STEP(t, ka, va, kc2, vc2);
    if (++t >= t1) break;
    STEP(t, kb_, vb_, ka, va);
    if (++t >= t1) break;
    STEP(t, kc2, vc2, kb_, vb_);
    if (++t >= t1) break;
  }
#undef STEP
#undef LOADK
#undef LOADV
}

// ---------- normalize + transpose (via private LDS) + coalesced O store ----------
__device__ __forceinline__ void attn_epilogue(
    const f32x16& accA, const f32x16& accB, float l_own, char* eb,
    unsigned short* __restrict__ O, int h, int qb, int wr, int q31, int hf) {
  float l_run;
  {
    unsigned a = __float_as_uint(l_own), b = a;
    permswap(a, b);
    l_run = __uint_as_float(a) + __uint_as_float(b);
  }
  const float inv = 1.0f / l_run;
#pragma unroll
  for (int dblk = 0; dblk < 2; ++dblk) {
#pragma unroll
    for (int tt = 0; tt < 4; ++tt) {
      float a0, a1, a2, a3;
      if (dblk == 0) { a0 = accA[4 * tt]; a1 = accA[4 * tt + 1]; a2 = accA[4 * tt + 2]; a3 = accA[4 * tt + 3]; }
      else           { a0 = accB[4 * tt]; a1 = accB[4 * tt + 1]; a2 = accB[4 * tt + 2]; a3 = accB[4 * tt + 3]; }
      unsigned d0 = cvtpk(a0 * inv, a1 * inv);
      unsigned d1 = cvtpk(a2 * inv, a3 * inv);
      int dbase = dblk * 32 + 8 * tt + 4 * hf;
      int off = (q31 * 128 + dbase * 2) ^ ((q31 & 7) << 4);
      *(uint2*)(eb + off) = make_uint2(d0, d1);
    }
  }
  const int lane = hf * 32 + q31;
  // same-wave RAW on LDS: compiler inserts lgkmcnt
#pragma unroll
  for (int pass = 0; pass < 4; ++pass) {
    int q = (lane >> 3) + pass * 8;
    int c8 = lane & 7;
    u16x8 vv = *(const u16x8*)(eb + ((q * 128 + c8 * 16) ^ ((q & 7) << 4)));
    *(u16x8*)(O + (size_t)(qb + wr * 32 + q) * HID + h * 64 + c8 * 8) = vv;
  }
}

// ---------- flash attention (causal): balanced pair + kv-split, 8 waves/block ----------
__global__ __launch_bounds__(512) void flash_attn(
    const unsigned short* __restrict__ Q,
    const unsigned short* __restrict__ Kf,
    const unsigned short* __restrict__ Vf,
    unsigned short* __restrict__ O) {
  __shared__ __attribute__((aligned(16))) unsigned short ebuf[8][2048];  // 32 KB
  __shared__ float part[4][64][33];                                      // 33.8 KB
  const int tid = threadIdx.x;
  const int wv = tid >> 6, lane = tid & 63;
  const int wr = wv & 3, role = wv >> 2;
  const int q31 = lane & 31, hf = lane >> 5;
  const int h = blockIdx.x;          // XCD = h % 8 -> K/V L2-resident (2 heads/XCD)
  const int p = blockIdx.y;
  const int tileB = 31 - p;
  const int nstA = 4 * p + wr + 1;
  const int nstB = 4 * tileB + wr + 1;
  const int cut = 62 - 4 * p;        // head/tail split of tile B (>=2 for p<=15)

  const unsigned short* kfb = Kf + (size_t)h * 128 * 2048;
  const unsigned short* vfb = Vf + (size_t)h * 128 * 2048;
  const int kOffBase = hf * 256 + q31 * 8;
  const int vOffBase = hf * 512 + q31 * 8;
  char* eb = (char*)&ebuf[wv][0];

  const int qgB = tileB * 128 + wr * 32 + q31;
  u16x8 qfB[4];
  {
    const unsigned short* qp = Q + ((size_t)h * S_LEN + qgB) * 64 + hf * 8;
#pragma unroll
    for (int c = 0; c < 4; ++c) qfB[c] = *(const u16x8*)(qp + c * 16);
  }

  if (role == 0) {
    // ---- tile A (= p) full triangle ----
    const int qgA = p * 128 + wr * 32 + q31;
    u16x8 qfA[4];
    {
      const unsigned short* qp = Q + ((size_t)h * S_LEN + qgA) * 64 + hf * 8;
#pragma unroll
      for (int c = 0; c < 4; ++c) qfA[c] = *(const u16x8*)(qp + c * 16);
    }
    f32x16 accA = {}, accB = {};
    float l_own = 0.f;
    attn_range(kfb, vfb, qfA, accA, accB, l_own, 0, nstA, nstA, qgA, hf, kOffBase, vOffBase);
    attn_epilogue(accA, accB, l_own, eb, O, h, p * 128, wr, q31, hf);
    // ---- tile B head [0, cut) ----
    f32x16 bA = {}, bB = {};
    float bl = 0.f;
    attn_range(kfb, vfb, qfB, bA, bB, bl, 0, cut, nstB, qgB, hf, kOffBase, vOffBase);
    float* pp = &part[wr][lane][0];
#pragma unroll
    for (int r = 0; r < 16; ++r) { pp[r] = bA[r]; pp[16 + r] = bB[r]; }
    pp[32] = bl;
    __syncthreads();
  } else {
    // ---- tile B tail [cut, nstB) (includes diagonal) ----
    f32x16 bA = {}, bB = {};
    float bl = 0.f;
    attn_range(kfb, vfb, qfB, bA, bB, bl, cut, nstB, nstB, qgB, hf, kOffBase, vOffBase);
    __syncthreads();
    const float* pp = &part[wr][lane][0];
#pragma unroll
    for (int r = 0; r < 16; ++r) { bA[r] += pp[r]; bB[r] += pp[16 + r]; }
    bl += pp[32];
    attn_epilogue(bA, bB, bl, eb, O, h, tileB * 128, wr, q31, hf);
  }
}

extern "C" void kernel_launch(void* const* d_in, const int* in_sizes, int n_in,
                              void* d_out, int out_size, void* d_ws, size_t ws_size,
                              hipStream_t stream) {
  const float* x = (const float*)d_in[0];       // [4096][1024]
  const float* w_qkv = (const float*)d_in[1];   // [3072][1024]
  const float* w_out = (const float*)d_in[2];   // [1024][1024]
  float* out = (float*)d_out;                   // [4096][1024] f32
  char* ws = (char*)d_ws;

  unsigned short* xb    = (unsigned short*)(ws + 0);          // 8 MB
  unsigned short* wqkvb = (unsigned short*)(ws + 8388608);    // 6 MB
  unsigned short* woutb = (unsigned short*)(ws + 14680064);   // 2 MB
  unsigned short* qkvb  = (unsigned short*)(ws + 16777216);   // 24 MB [S][3072]
  unsigned short* Qb    = (unsigned short*)(ws + 41943040);   // 8 MB [H][S][64]
  unsigned short* Kfb   = (unsigned short*)(ws + 50331648);   // 8 MB fragment-major
  unsigned short* Vfb   = (unsigned short*)(ws + 58720256);   // 8 MB fragment-major
  unsigned short* attnb = (unsigned short*)(ws + 67108864);   // 8 MB [S][1024]

  k_cvt_all<<<dim3(8192), dim3(256), 0, stream>>>(
      (const float4*)x, (const float4*)w_qkv, (const float4*)w_out,
      (ushort4*)xb, (ushort4*)wqkvb, (ushort4*)woutb);

  gemm_bt<unsigned short><<<dim3(24, 32), dim3(256), 0, stream>>>(xb, wqkvb, qkvb, 4096, 3072, 1024);

  k_rope_split<<<dim3(4096), dim3(512), 0, stream>>>(qkvb, Qb, Kfb);
  k_vt<<<dim3(64, 16), dim3(256), 0, stream>>>(qkvb, Vfb);

  // balanced pair + kv-split grid: blockId = h + 16*p -> XCD = h%8
  flash_attn<<<dim3(16, 16), dim3(512), 0, stream>>>(Qb, Kfb, Vfb, attnb);

  gemm_bt<float><<<dim3(8, 32), dim3(256), 0, stream>>>(attnb, woutb, out, 4096, 1024, 1024);
}